// Round 11
// baseline (444.991 us; speedup 1.0000x reference)
//
#include <hip/hip_runtime.h>
#include <hip/hip_bf16.h>
#include <cmath>

#define B_SZ 8
#define L_SZ 2048
#define DM 512
#define DI 1024
#define DS 16
#define DC 4
#define DTR 32
#define NE 4
#define NL 2
#define NCH 64
#define TC2 32   // timesteps per chunk = L_SZ / NCH
#define TPER 8   // timesteps per conv thread

typedef __attribute__((ext_vector_type(8))) short bf16x8;
typedef __attribute__((ext_vector_type(8))) unsigned short u16x8;
typedef __attribute__((ext_vector_type(4))) float f32x4;

__device__ __forceinline__ unsigned short f2bf(float x) {
  __hip_bfloat16 h = __float2bfloat16(x);
  return __builtin_bit_cast(unsigned short, h);
}
__device__ __forceinline__ float bf2f(unsigned short u) {
  return __builtin_bit_cast(float, (unsigned)u << 16);
}

// async global(16B/lane) -> LDS (wave-uniform base + lane*16)
__device__ __forceinline__ void glds16(const unsigned short* g, unsigned short* l) {
  __builtin_amdgcn_global_load_lds(
      (const __attribute__((address_space(1))) unsigned int*)g,
      (__attribute__((address_space(3))) unsigned int*)l, 16, 0, 0);
}

// fast softplus
__device__ __forceinline__ float softplus_fast(float v) {
  return (v > 20.f) ? v : __logf(1.f + __expf(v));
}

// powers g^1..g^16 with dependency depth <=5 (binary composition)
__device__ __forceinline__ void pow16(float g, float* ee) {
  float g2 = g * g, g4 = g2 * g2, g8 = g4 * g4;
  ee[0] = g;        ee[1] = g2;       ee[2] = g2 * g;   ee[3] = g4;
  ee[4] = g4 * g;   ee[5] = g4 * g2;  ee[6] = ee[5] * g; ee[7] = g8;
  ee[8] = g8 * g;   ee[9] = g8 * g2;  ee[10] = ee[9] * g; ee[11] = g8 * g4;
  ee[12] = ee[11] * g; ee[13] = ee[11] * g2; ee[14] = ee[13] * g; ee[15] = g8 * g8;
}

// ---------------------------------------------------------------------------
// Transpose + fp32->bf16: in fp32 [P][R][C] -> out bf16 [P][C][R]
// ---------------------------------------------------------------------------
__global__ __launch_bounds__(256) void transpose_w_kernel(
    const float* __restrict__ in, unsigned short* __restrict__ out, int R, int C)
{
  __shared__ float t[32][33];
  const int p = blockIdx.z;
  const int r0 = blockIdx.y * 32, c0 = blockIdx.x * 32;
  const int tx = threadIdx.x & 31, ty = threadIdx.x >> 5;
  const float* ip = in + (long)p * R * C;
  unsigned short* op = out + (long)p * R * C;
  #pragma unroll
  for (int i = 0; i < 32; i += 8)
    t[ty + i][tx] = ip[(long)(r0 + ty + i) * C + c0 + tx];
  __syncthreads();
  #pragma unroll
  for (int i = 0; i < 32; i += 8)
    op[(long)(c0 + ty + i) * R + r0 + tx] = f2bf(t[tx][ty + i]);
}

// fp32 -> bf16 elementwise (x shadow)
__global__ __launch_bounds__(256) void f2bf_kernel(
    const float* __restrict__ in, unsigned short* __restrict__ out)
{
  long i = ((long)blockIdx.x * 256 + threadIdx.x) * 4;
  float4 v = *(const float4*)(in + i);
  out[i + 0] = f2bf(v.x); out[i + 1] = f2bf(v.y);
  out[i + 2] = f2bf(v.z); out[i + 3] = f2bf(v.w);
}

// ---------------------------------------------------------------------------
// bf16 MFMA GEMM, global_load_lds staging, BK=32 (m97-proven LDS budget),
// bank-conflict-free (pre-swizzled global source + swizzled read; rule 21),
// XCD-aware block swizzle (T1): contiguous work chunk per XCD -> per-XCD L2
// holds one sample's A-panel + its expert weights.
// ---------------------------------------------------------------------------
template<int EPI, int TM, int TN>
__global__ __launch_bounds__(256) void gemm_bf16(
    const unsigned short* __restrict__ Abase, long aBatch, int K, int lda,
    const unsigned short* __restrict__ WTbase, long wStride,
    const float* __restrict__ xpass,
    const int* __restrict__ expert_id, int layer,
    float* __restrict__ Cf, unsigned short* __restrict__ Cbh,
    unsigned short* __restrict__ Cbh2,
    int ldc, long cBatch)
{
  constexpr int IF = TM / 32;
  constexpr int JF = TN / 32;
  constexpr int AST = TM / 4;
  constexpr int BST = TN / 4;

  // XCD-aware swizzle (grid size is a multiple of 8 for all instantiations)
  const int nbx = gridDim.x, nby = gridDim.y;
  const int fid = blockIdx.x + nbx * (blockIdx.y + nby * blockIdx.z);
  const int cpx = (nbx * nby * gridDim.z) >> 3;
  const int swz = (fid & 7) * cpx + (fid >> 3);
  const int bx = swz % nbx;
  const int tq = swz / nbx;
  const int by = tq % nby;
  const int b  = tq / nby;

  const int eid = expert_id[b];
  const int m0 = by * TM, n0 = bx * TN;
  const int tid = threadIdx.x;

  if (eid == 0) {
    if (EPI == 2) {
      float* Co = Cf + (long)b * cBatch;
      const float* xp = xpass + (long)b * L_SZ * DM;
      for (int i = tid; i < TM * TN; i += 256) {
        int r = m0 + (i / TN), c = n0 + (i % TN);
        Co[(long)r * ldc + c] = xp[(long)r * DM + c];
      }
    }
    return;
  }
  const int e = min(max(eid - 1, 0), NE - 1);
  const unsigned short* A = Abase + (long)b * aBatch;
  const unsigned short* WT = WTbase + (long)(e * NL + layer) * wStride;

  __shared__ unsigned short As[TM * 32];
  __shared__ unsigned short Bs[TN * 32];

  const int w = tid >> 6, lane = tid & 63;
  const int srow = lane >> 2;
  const int sgsw = ((lane & 3) ^ ((srow >> 1) & 3)) * 8;  // swizzled k-chunk

  const unsigned short* aG0 = A + (long)(m0 + w * AST + srow) * lda + sgsw;
  const unsigned short* aG1 = aG0 + 16 * lda;
  unsigned short* aL0 = As + (w * AST) * 32;
  unsigned short* aL1 = As + (w * AST + 16) * 32;
  const unsigned short* bG0 = WT + (long)(n0 + w * BST + srow) * K + sgsw;
  const unsigned short* bG1 = bG0 + 16 * K;
  unsigned short* bL0 = Bs + (w * BST) * 32;
  unsigned short* bL1 = Bs + (w * BST + 16) * 32;

  const int wm = w >> 1, wn = w & 1;
  const int lo = lane & 15, hi = lane >> 4;
  int aoff[IF], boff[JF];
  #pragma unroll
  for (int i = 0; i < IF; ++i)
    aoff[i] = (wm * (TM / 2) + i * 16 + lo) * 32 + (hi ^ ((lo >> 1) & 3)) * 8;
  #pragma unroll
  for (int j = 0; j < JF; ++j)
    boff[j] = (wn * (TN / 2) + j * 16 + lo) * 32 + (hi ^ ((lo >> 1) & 3)) * 8;

  f32x4 acc[IF][JF] = {};

  for (int k0 = 0; k0 < K; k0 += 32) {
    glds16(aG0 + k0, aL0);
    if (AST == 32) glds16(aG1 + k0, aL1);
    glds16(bG0 + k0, bL0);
    if (BST == 32) glds16(bG1 + k0, bL1);
    __syncthreads();

    bf16x8 af[IF], bfr[JF];
    #pragma unroll
    for (int i = 0; i < IF; ++i) af[i] = *(const bf16x8*)(As + aoff[i]);
    #pragma unroll
    for (int j = 0; j < JF; ++j) bfr[j] = *(const bf16x8*)(Bs + boff[j]);
    #pragma unroll
    for (int i = 0; i < IF; ++i)
      #pragma unroll
      for (int j = 0; j < JF; ++j)
        acc[i][j] = __builtin_amdgcn_mfma_f32_16x16x32_bf16(af[i], bfr[j], acc[i][j], 0, 0, 0);
    __syncthreads();
  }

  #pragma unroll
  for (int i = 0; i < IF; ++i) {
    #pragma unroll
    for (int j = 0; j < JF; ++j) {
      #pragma unroll
      for (int r = 0; r < 4; ++r) {
        int row = m0 + wm * (TM / 2) + i * 16 + hi * 4 + r;
        int col = n0 + wn * (TN / 2) + j * 16 + lo;
        float v = acc[i][j][r];
        if (EPI == 0 || EPI == 2) {
          (Cf + (long)b * cBatch)[(long)row * ldc + col] = v;
        } else if (EPI == 4) {
          (Cbh + (long)b * cBatch)[(long)row * ldc + col] = f2bf(v);
        } else {  // EPI 3: split xc | res, both bf16
          if (col < DI)
            (Cbh + (long)b * cBatch)[(long)row * DI + col] = f2bf(v);
          else
            (Cbh2 + (long)b * cBatch)[(long)row * DI + (col - DI)] = f2bf(v);
        }
      }
    }
  }
}

// ---------------------------------------------------------------------------
// dt GEMM (fp32 A, K=32): DT = softplus(PR[:, :32] @ W_dt + b_dt), bf16 out.
// ---------------------------------------------------------------------------
__global__ __launch_bounds__(256) void gemm_dt(
    const float* __restrict__ PRb, const unsigned short* __restrict__ WTbase,
    const float* __restrict__ biasBase,
    const int* __restrict__ expert_id, int layer,
    unsigned short* __restrict__ DTout)
{
  const int b = blockIdx.z;
  const int eid = expert_id[b];
  if (eid == 0) return;
  const int e = min(max(eid - 1, 0), NE - 1);
  const int m0 = blockIdx.y * 128, n0 = blockIdx.x * 128;
  const int tid = threadIdx.x;
  const float* A = PRb + (long)b * L_SZ * 64;
  const unsigned short* WT = WTbase + (long)(e * NL + layer) * DI * DTR;

  __shared__ unsigned short As[128 * 32];
  __shared__ unsigned short Bs[128 * 32];

  const int sr = tid >> 2, sg = tid & 3;
  const int slot = sg ^ ((sr >> 1) & 3);

  {
    float4 fa0 = *(const float4*)(A + (long)(m0 + sr) * 64 + sg * 8);
    float4 fa1 = *(const float4*)(A + (long)(m0 + sr) * 64 + sg * 8 + 4);
    float4 fb0 = *(const float4*)(A + (long)(m0 + sr + 64) * 64 + sg * 8);
    float4 fb1 = *(const float4*)(A + (long)(m0 + sr + 64) * 64 + sg * 8 + 4);
    u16x8 w0 = *(const u16x8*)(WT + (long)(n0 + sr) * DTR + sg * 8);
    u16x8 w1 = *(const u16x8*)(WT + (long)(n0 + sr + 64) * DTR + sg * 8);
    u16x8 ha = {f2bf(fa0.x), f2bf(fa0.y), f2bf(fa0.z), f2bf(fa0.w),
                f2bf(fa1.x), f2bf(fa1.y), f2bf(fa1.z), f2bf(fa1.w)};
    u16x8 hb = {f2bf(fb0.x), f2bf(fb0.y), f2bf(fb0.z), f2bf(fb0.w),
                f2bf(fb1.x), f2bf(fb1.y), f2bf(fb1.z), f2bf(fb1.w)};
    *(u16x8*)(As + sr * 32 + slot * 8) = ha;
    *(u16x8*)(As + (sr + 64) * 32 + slot * 8) = hb;
    *(u16x8*)(Bs + sr * 32 + slot * 8) = w0;
    *(u16x8*)(Bs + (sr + 64) * 32 + slot * 8) = w1;
  }
  __syncthreads();

  const int lane = tid & 63, w = tid >> 6;
  const int wm = w >> 1, wn = w & 1;
  const int lo = lane & 15, hi = lane >> 4;
  f32x4 acc[4][4] = {};
  bf16x8 af[4], bfr[4];
  #pragma unroll
  for (int i = 0; i < 4; ++i) {
    int r = wm * 64 + i * 16 + lo;
    af[i] = *(const bf16x8*)(As + r * 32 + (hi ^ ((r >> 1) & 3)) * 8);
  }
  #pragma unroll
  for (int j = 0; j < 4; ++j) {
    int r = wn * 64 + j * 16 + lo;
    bfr[j] = *(const bf16x8*)(Bs + r * 32 + (hi ^ ((r >> 1) & 3)) * 8);
  }
  #pragma unroll
  for (int i = 0; i < 4; ++i)
    #pragma unroll
    for (int j = 0; j < 4; ++j)
      acc[i][j] = __builtin_amdgcn_mfma_f32_16x16x32_bf16(af[i], bfr[j], acc[i][j], 0, 0, 0);

  const float* bias = biasBase + (long)(e * NL + layer) * DI;
  unsigned short* Cb = DTout + (long)b * L_SZ * DI;
  #pragma unroll
  for (int i = 0; i < 4; ++i)
    #pragma unroll
    for (int j = 0; j < 4; ++j)
      #pragma unroll
      for (int r = 0; r < 4; ++r) {
        int row = m0 + wm * 64 + i * 16 + hi * 4 + r;
        int col = n0 + wn * 64 + j * 16 + lo;
        float v = softplus_fast(acc[i][j][r] + bias[col]);
        Cb[(long)row * DI + col] = f2bf(v);
      }
}

// ---------------------------------------------------------------------------
// Causal depthwise conv (DC=4) + SiLU, t-blocked.
// ---------------------------------------------------------------------------
__global__ __launch_bounds__(256) void conv_silu_kernel(
    const unsigned short* __restrict__ XCP,
    const float* __restrict__ conv_w, const float* __restrict__ conv_b,
    const int* __restrict__ expert_id, int layer,
    unsigned short* __restrict__ XCbf)
{
  const int idx = blockIdx.x * 256 + threadIdx.x;
  const int d8 = idx & 127;
  const int tb = (idx >> 7) & (L_SZ / TPER - 1);
  const int b = idx >> 15;
  const int eid = expert_id[b];
  if (eid == 0) return;
  const int e = min(max(eid - 1, 0), NE - 1);
  const int d0 = d8 * 8;
  const int t0 = tb * TPER;

  const float* cwp = conv_w + ((long)(e * NL + layer) * DI + d0) * DC;
  float4 w4[8];
  #pragma unroll
  for (int j = 0; j < 8; ++j) w4[j] = *(const float4*)(cwp + j * 4);
  float cb[8];
  {
    const float* cbp = conv_b + (long)(e * NL + layer) * DI + d0;
    float4 c0 = *(const float4*)(cbp);
    float4 c1 = *(const float4*)(cbp + 4);
    cb[0] = c0.x; cb[1] = c0.y; cb[2] = c0.z; cb[3] = c0.w;
    cb[4] = c1.x; cb[5] = c1.y; cb[6] = c1.z; cb[7] = c1.w;
  }

  const unsigned short* base = XCP + ((long)b * L_SZ + t0) * DI + d0;
  u16x8 r[TPER + 3];
  #pragma unroll
  for (int i = 0; i < TPER + 3; ++i) {
    if (t0 - 3 + i < 0) {
      u16x8 z = {0, 0, 0, 0, 0, 0, 0, 0};
      r[i] = z;
    } else {
      r[i] = *(const u16x8*)(base + (long)(i - 3) * DI);
    }
  }

  unsigned short* ob = XCbf + ((long)b * L_SZ + t0) * DI + d0;
  #pragma unroll
  for (int j = 0; j < TPER; ++j) {
    u16x8 o;
    #pragma unroll
    for (int ch = 0; ch < 8; ++ch) {
      float acc = cb[ch];
      acc = fmaf(bf2f(r[j + 0][ch]), w4[ch].x, acc);
      acc = fmaf(bf2f(r[j + 1][ch]), w4[ch].y, acc);
      acc = fmaf(bf2f(r[j + 2][ch]), w4[ch].z, acc);
      acc = fmaf(bf2f(r[j + 3][ch]), w4[ch].w, acc);
      float v = acc / (1.f + __expf(-acc));
      o[ch] = f2bf(v);
    }
    *(u16x8*)(ob + (long)j * DI) = o;
  }
}

// ---------------------------------------------------------------------------
// Chunked scan pass 1: local scan from h=0 -> Hws (h_end), Sws (sum dt).
// 4-t software pipeline: scalar loads hoisted per 4-t batch.
// ---------------------------------------------------------------------------
__global__ __launch_bounds__(256) void scan_p1(
    const unsigned short* __restrict__ DTb, const unsigned short* __restrict__ XCbf,
    const float* __restrict__ PR, const float* __restrict__ A_log,
    const int* __restrict__ expert_id, int layer,
    float* __restrict__ Hws, float* __restrict__ Sws)
{
  const int b = blockIdx.z, c = blockIdx.y;
  const int eid = expert_id[b];
  if (eid == 0) return;
  const int e = min(max(eid - 1, 0), NE - 1);
  const int d = blockIdx.x * 256 + threadIdx.x;
  const int t0 = c * TC2;

  __shared__ float sB[TC2][16];
  const float* prb = PR + (long)b * L_SZ * 64;
  for (int i = threadIdx.x; i < TC2 * 16; i += 256) {
    int t = i >> 4, s = i & 15;
    sB[t][s] = prb[(long)(t0 + t) * 64 + DTR + s];
  }

  float Aval[16];
  const float* al = A_log + ((long)(e * NL + layer) * DI + d) * DS;
  #pragma unroll
  for (int s = 0; s < 16; ++s) Aval[s] = -__expf(al[s]);
  bool geo = true;
  #pragma unroll
  for (int s = 1; s < 16; ++s)
    geo = geo && (fabsf(Aval[s] - Aval[0] * (s + 1)) <= 1e-4f * (s + 1));

  float h[16];
  #pragma unroll
  for (int s = 0; s < 16; ++s) h[s] = 0.f;
  float S = 0.f;

  const unsigned short* dtp = DTb + ((long)b * L_SZ + t0) * DI + d;
  const unsigned short* xcp = XCbf + ((long)b * L_SZ + t0) * DI + d;
  __syncthreads();

  const float A0 = Aval[0];
  for (int t4 = 0; t4 < TC2; t4 += 4) {
    float dt4[4], xc4[4];
    #pragma unroll
    for (int k = 0; k < 4; ++k) {
      dt4[k] = bf2f(dtp[(long)(t4 + k) * DI]);
      xc4[k] = bf2f(xcp[(long)(t4 + k) * DI]);
    }
    if (geo) {
      #pragma unroll
      for (int k = 0; k < 4; ++k) {
        int t = t4 + k;
        float dt = dt4[k];
        S += dt;
        float dx = dt * xc4[k];
        float4 b0 = *(const float4*)&sB[t][0];
        float4 b1 = *(const float4*)&sB[t][4];
        float4 b2 = *(const float4*)&sB[t][8];
        float4 b3 = *(const float4*)&sB[t][12];
        float bv[16] = {b0.x, b0.y, b0.z, b0.w, b1.x, b1.y, b1.z, b1.w,
                        b2.x, b2.y, b2.z, b2.w, b3.x, b3.y, b3.z, b3.w};
        float ee[16];
        pow16(__expf(dt * A0), ee);
        #pragma unroll
        for (int s = 0; s < 16; ++s)
          h[s] = fmaf(ee[s], h[s], dx * bv[s]);
      }
    } else {
      #pragma unroll
      for (int k = 0; k < 4; ++k) {
        int t = t4 + k;
        float dt = dt4[k];
        S += dt;
        float dx = dt * xc4[k];
        float4 b0 = *(const float4*)&sB[t][0];
        float4 b1 = *(const float4*)&sB[t][4];
        float4 b2 = *(const float4*)&sB[t][8];
        float4 b3 = *(const float4*)&sB[t][12];
        float bv[16] = {b0.x, b0.y, b0.z, b0.w, b1.x, b1.y, b1.z, b1.w,
                        b2.x, b2.y, b2.z, b2.w, b3.x, b3.y, b3.z, b3.w};
        #pragma unroll
        for (int s = 0; s < 16; ++s)
          h[s] = fmaf(__expf(dt * Aval[s]), h[s], dx * bv[s]);
      }
    }
  }

  const long hoff = (((long)b * NCH + c) * DI + d) * 16;
  #pragma unroll
  for (int s = 0; s < 16; s += 4)
    *(float4*)&Hws[hoff + s] = make_float4(h[s], h[s + 1], h[s + 2], h[s + 3]);
  Sws[((long)b * NCH + c) * DI + d] = S;
}

// ---------------------------------------------------------------------------
// Chunk combine (in-place): Hws[c] := h_in(c)
// ---------------------------------------------------------------------------
__global__ __launch_bounds__(256) void scan_combine(
    float* __restrict__ Hws, const float* __restrict__ Sws,
    const float* __restrict__ A_log,
    const int* __restrict__ expert_id, int layer)
{
  const int gid = blockIdx.x * 256 + threadIdx.x;
  const int s = gid & 15;
  const int d = (gid >> 4) & (DI - 1);
  const int b = gid >> 14;
  const int eid = expert_id[b];
  if (eid == 0) return;
  const int e = min(max(eid - 1, 0), NE - 1);
  const float Aval = -__expf(A_log[((long)(e * NL + layer) * DI + d) * DS + s]);
  float h = 0.f;
  for (int c = 0; c < NCH; ++c) {
    const long off = (((long)b * NCH + c) * DI + d) * 16 + s;
    float q = Hws[off];
    float Sc = Sws[((long)b * NCH + c) * DI + d];
    Hws[off] = h;
    h = fmaf(__expf(Aval * Sc), h, q);
  }
}

// ---------------------------------------------------------------------------
// Chunked scan pass 2: re-scan seeded with h_in; y=(h@C + D*xc)*silu(res) -> bf16
// 4-t software pipeline + 4-way split y accumulator + binary-power ee.
// ---------------------------------------------------------------------------
__global__ __launch_bounds__(256) void scan_p2(
    const unsigned short* __restrict__ DTb, const unsigned short* __restrict__ XCbf,
    const unsigned short* __restrict__ RESb, const float* __restrict__ PR,
    const float* __restrict__ A_log, const float* __restrict__ Dw,
    const float* __restrict__ Hws,
    const int* __restrict__ expert_id, int layer,
    unsigned short* __restrict__ Ybf)
{
  const int b = blockIdx.z, c = blockIdx.y;
  const int eid = expert_id[b];
  if (eid == 0) return;
  const int e = min(max(eid - 1, 0), NE - 1);
  const int d = blockIdx.x * 256 + threadIdx.x;
  const int t0 = c * TC2;

  __shared__ float sBC[TC2][32];
  const float* prb = PR + (long)b * L_SZ * 64;
  for (int i = threadIdx.x; i < TC2 * 32; i += 256) {
    int t = i >> 5, j = i & 31;
    sBC[t][j] = prb[(long)(t0 + t) * 64 + DTR + j];
  }

  float Aval[16];
  const float* al = A_log + ((long)(e * NL + layer) * DI + d) * DS;
  #pragma unroll
  for (int s = 0; s < 16; ++s) Aval[s] = -__expf(al[s]);
  bool geo = true;
  #pragma unroll
  for (int s = 1; s < 16; ++s)
    geo = geo && (fabsf(Aval[s] - Aval[0] * (s + 1)) <= 1e-4f * (s + 1));

  float h[16];
  const long hoff = (((long)b * NCH + c) * DI + d) * 16;
  #pragma unroll
  for (int s = 0; s < 16; s += 4) {
    float4 hv = *(const float4*)&Hws[hoff + s];
    h[s] = hv.x; h[s + 1] = hv.y; h[s + 2] = hv.z; h[s + 3] = hv.w;
  }
  const float Dd = Dw[(long)(e * NL + layer) * DI + d];

  const unsigned short* dtp = DTb + ((long)b * L_SZ + t0) * DI + d;
  const unsigned short* xcp = XCbf + ((long)b * L_SZ + t0) * DI + d;
  const unsigned short* rsp = RESb + ((long)b * L_SZ + t0) * DI + d;
  unsigned short* yb = Ybf + ((long)b * L_SZ + t0) * DI + d;
  __syncthreads();

  const float A0 = Aval[0];
  for (int t4 = 0; t4 < TC2; t4 += 4) {
    float dt4[4], xc4[4], rs4[4];
    #pragma unroll
    for (int k = 0; k < 4; ++k) {
      dt4[k] = bf2f(dtp[(long)(t4 + k) * DI]);
      xc4[k] = bf2f(xcp[(long)(t4 + k) * DI]);
      rs4[k] = bf2f(rsp[(long)(t4 + k) * DI]);
    }
    unsigned short yo[4];
    #pragma unroll
    for (int k = 0; k < 4; ++k) {
      int t = t4 + k;
      float dt = dt4[k], xc = xc4[k], res = rs4[k];
      float dx = dt * xc;
      float4 b0 = *(const float4*)&sBC[t][0];
      float4 b1 = *(const float4*)&sBC[t][4];
      float4 b2 = *(const float4*)&sBC[t][8];
      float4 b3 = *(const float4*)&sBC[t][12];
      float4 c0 = *(const float4*)&sBC[t][16];
      float4 c1 = *(const float4*)&sBC[t][20];
      float4 c2 = *(const float4*)&sBC[t][24];
      float4 c3 = *(const float4*)&sBC[t][28];
      float bv[16] = {b0.x, b0.y, b0.z, b0.w, b1.x, b1.y, b1.z, b1.w,
                      b2.x, b2.y, b2.z, b2.w, b3.x, b3.y, b3.z, b3.w};
      float cv[16] = {c0.x, c0.y, c0.z, c0.w, c1.x, c1.y, c1.z, c1.w,
                      c2.x, c2.y, c2.z, c2.w, c3.x, c3.y, c3.z, c3.w};
      float y0 = 0.f, y1 = 0.f, y2 = 0.f, y3 = 0.f;
      if (geo) {
        float ee[16];
        pow16(__expf(dt * A0), ee);
        #pragma unroll
        for (int s = 0; s < 16; s += 4) {
          h[s]     = fmaf(ee[s],     h[s],     dx * bv[s]);
          h[s + 1] = fmaf(ee[s + 1], h[s + 1], dx * bv[s + 1]);
          h[s + 2] = fmaf(ee[s + 2], h[s + 2], dx * bv[s + 2]);
          h[s + 3] = fmaf(ee[s + 3], h[s + 3], dx * bv[s + 3]);
          y0 = fmaf(h[s],     cv[s],     y0);
          y1 = fmaf(h[s + 1], cv[s + 1], y1);
          y2 = fmaf(h[s + 2], cv[s + 2], y2);
          y3 = fmaf(h[s + 3], cv[s + 3], y3);
        }
      } else {
        #pragma unroll
        for (int s = 0; s < 16; s += 4) {
          h[s]     = fmaf(__expf(dt * Aval[s]),     h[s],     dx * bv[s]);
          h[s + 1] = fmaf(__expf(dt * Aval[s + 1]), h[s + 1], dx * bv[s + 1]);
          h[s + 2] = fmaf(__expf(dt * Aval[s + 2]), h[s + 2], dx * bv[s + 2]);
          h[s + 3] = fmaf(__expf(dt * Aval[s + 3]), h[s + 3], dx * bv[s + 3]);
          y0 = fmaf(h[s],     cv[s],     y0);
          y1 = fmaf(h[s + 1], cv[s + 1], y1);
          y2 = fmaf(h[s + 2], cv[s + 2], y2);
          y3 = fmaf(h[s + 3], cv[s + 3], y3);
        }
      }
      float y = (y0 + y1) + (y2 + y3);
      y = fmaf(Dd, xc, y);
      float sil = res / (1.f + __expf(-res));
      yo[k] = f2bf(y * sil);
    }
    #pragma unroll
    for (int k = 0; k < 4; ++k)
      yb[(long)(t4 + k) * DI] = yo[k];
  }
}

// ---------------------------------------------------------------------------
extern "C" void kernel_launch(void* const* d_in, const int* in_sizes, int n_in,
                              void* d_out, int out_size, void* d_ws, size_t ws_size,
                              hipStream_t stream)
{
  const float* x      = (const float*)d_in[0];
  const int*   eidp   = (const int*)d_in[1];
  const float* W_in   = (const float*)d_in[2];
  const float* conv_w = (const float*)d_in[3];
  const float* conv_b = (const float*)d_in[4];
  const float* W_x    = (const float*)d_in[5];
  const float* W_dt   = (const float*)d_in[6];
  const float* b_dt   = (const float*)d_in[7];
  const float* A_log  = (const float*)d_in[8];
  const float* Dw     = (const float*)d_in[9];
  const float* W_out  = (const float*)d_in[10];
  float* out = (float*)d_out;
  float* ws  = (float*)d_ws;

  // workspace layout — total ~207.5 MB (< proven-safe 265.8 MB)
  float* PR  = ws;                          //  1,048,576 f32 ( 4 MB)
  float* Hws = PR + 1048576L;               //  8,388,608 f32 (32 MB)
  float* Sws = Hws + 8388608L;              //    524,288 f32 ( 2 MB)
  unsigned short* DTb  = (unsigned short*)(Sws + 524288L);  // 32 MB
  unsigned short* XCP  = DTb + 16777216L;                   // 32 MB
  unsigned short* Ybf  = XCP;                               // overlay (disjoint liveness)
  unsigned short* XCbf = XCP + 16777216L;                   // 32 MB
  unsigned short* RESb = XCbf + 16777216L;                  // 32 MB
  unsigned short* XB   = RESb + 16777216L;                  // 16 MB (x shadow / XN)
  unsigned short* WinT  = XB + 8388608L;                    // 16 MB
  unsigned short* WoutT = WinT + 8388608L;                  //  8 MB
  unsigned short* WxT   = WoutT + 4194304L;                 //  1 MB
  unsigned short* WdtT  = WxT + 524288L;                    // 0.5 MB

  transpose_w_kernel<<<dim3(2 * DI / 32, DM / 32, NE * NL), 256, 0, stream>>>(
      W_in, WinT, DM, 2 * DI);
  transpose_w_kernel<<<dim3(DM / 32, DI / 32, NE * NL), 256, 0, stream>>>(
      W_out, WoutT, DI, DM);
  transpose_w_kernel<<<dim3(2, DI / 32, NE * NL), 256, 0, stream>>>(
      W_x, WxT, DI, 64);
  transpose_w_kernel<<<dim3(DI / 32, 1, NE * NL), 256, 0, stream>>>(
      W_dt, WdtT, DTR, DI);
  f2bf_kernel<<<8192, 256, 0, stream>>>(x, XB);

  for (int l = 0; l < NL; ++l) {
    // 1) xr = xin @ W_in  (M=2048 N=2048 K=512): split -> XCP bf16 | RESb bf16
    gemm_bf16<3, 128, 128><<<dim3(2 * DI / 128, L_SZ / 128, B_SZ), 256, 0, stream>>>(
        XB, (long)L_SZ * DM, DM, DM, WinT, (long)(2 * DI) * DM,
        nullptr, eidp, l, nullptr, XCP, RESb, 0, (long)L_SZ * DI);

    // 2) conv + silu -> XCbf bf16
    conv_silu_kernel<<<B_SZ * (L_SZ / TPER) * 128 / 256, 256, 0, stream>>>(
        XCP, conv_w, conv_b, eidp, l, XCbf);

    // 3) proj = xc @ W_x -> PR fp32  (M=2048 N=64 K=1024, TM=TN=64)
    gemm_bf16<0, 64, 64><<<dim3(1, L_SZ / 64, B_SZ), 256, 0, stream>>>(
        XCbf, (long)L_SZ * DI, DI, DI, WxT, (long)64 * DI,
        nullptr, eidp, l, PR, nullptr, nullptr, 64, (long)L_SZ * 64);

    // 4) dt = softplus(PR[:,:32] @ W_dt + b_dt) -> DTb bf16
    gemm_dt<<<dim3(DI / 128, L_SZ / 128, B_SZ), 256, 0, stream>>>(
        PR, WdtT, b_dt, eidp, l, DTb);

    // 5) chunked scan -> Ybf bf16 (overlays XCP, dead after conv)
    scan_p1<<<dim3(DI / 256, NCH, B_SZ), 256, 0, stream>>>(
        DTb, XCbf, PR, A_log, eidp, l, Hws, Sws);
    scan_combine<<<(B_SZ * DI * DS) / 256, 256, 0, stream>>>(
        Hws, Sws, A_log, eidp, l);
    scan_p2<<<dim3(DI / 256, NCH, B_SZ), 256, 0, stream>>>(
        DTb, XCbf, RESb, PR, A_log, Dw, Hws, eidp, l, Ybf);

    // 6) y @ W_out  (M=2048 N=512 K=1024)
    if (l == NL - 1) {
      gemm_bf16<2, 128, 128><<<dim3(DM / 128, L_SZ / 128, B_SZ), 256, 0, stream>>>(
          Ybf, (long)L_SZ * DI, DI, DI, WoutT, (long)DM * DI,
          x, eidp, l, out, nullptr, nullptr, DM, (long)L_SZ * DM);
    } else {
      gemm_bf16<4, 128, 128><<<dim3(DM / 128, L_SZ / 128, B_SZ), 256, 0, stream>>>(
          Ybf, (long)L_SZ * DI, DI, DI, WoutT, (long)DM * DI,
          nullptr, eidp, l, nullptr, XB, nullptr, DM, (long)L_SZ * DM);
    }
  }
}

// Round 12
// 405.227 us; speedup vs baseline: 1.0981x; 1.0981x over previous
//
#include <hip/hip_runtime.h>
#include <hip/hip_bf16.h>
#include <cmath>

#define B_SZ 8
#define L_SZ 2048
#define DM 512
#define DI 1024
#define DS 16
#define DC 4
#define DTR 32
#define NE 4
#define NL 2
#define NCH 64
#define TC2 32   // timesteps per chunk = L_SZ / NCH
#define TPER 8   // timesteps per conv thread

typedef __attribute__((ext_vector_type(8))) short bf16x8;
typedef __attribute__((ext_vector_type(8))) unsigned short u16x8;
typedef __attribute__((ext_vector_type(4))) float f32x4;

__device__ __forceinline__ unsigned short f2bf(float x) {
  __hip_bfloat16 h = __float2bfloat16(x);
  return __builtin_bit_cast(unsigned short, h);
}
__device__ __forceinline__ float bf2f(unsigned short u) {
  return __builtin_bit_cast(float, (unsigned)u << 16);
}

// async global(16B/lane) -> LDS (wave-uniform base + lane*16)
__device__ __forceinline__ void glds16(const unsigned short* g, unsigned short* l) {
  __builtin_amdgcn_global_load_lds(
      (const __attribute__((address_space(1))) unsigned int*)g,
      (__attribute__((address_space(3))) unsigned int*)l, 16, 0, 0);
}

// fast softplus
__device__ __forceinline__ float softplus_fast(float v) {
  return (v > 20.f) ? v : __logf(1.f + __expf(v));
}

// powers g^1..g^16 with dependency depth <=5 (binary composition)
__device__ __forceinline__ void pow16(float g, float* ee) {
  float g2 = g * g, g4 = g2 * g2, g8 = g4 * g4;
  ee[0] = g;        ee[1] = g2;       ee[2] = g2 * g;   ee[3] = g4;
  ee[4] = g4 * g;   ee[5] = g4 * g2;  ee[6] = ee[5] * g; ee[7] = g8;
  ee[8] = g8 * g;   ee[9] = g8 * g2;  ee[10] = ee[9] * g; ee[11] = g8 * g4;
  ee[12] = ee[11] * g; ee[13] = ee[11] * g2; ee[14] = ee[13] * g; ee[15] = g8 * g8;
}

// ---------------------------------------------------------------------------
// Transpose + fp32->bf16: in fp32 [P][R][C] -> out bf16 [P][C][R]
// ---------------------------------------------------------------------------
__global__ __launch_bounds__(256) void transpose_w_kernel(
    const float* __restrict__ in, unsigned short* __restrict__ out, int R, int C)
{
  __shared__ float t[32][33];
  const int p = blockIdx.z;
  const int r0 = blockIdx.y * 32, c0 = blockIdx.x * 32;
  const int tx = threadIdx.x & 31, ty = threadIdx.x >> 5;
  const float* ip = in + (long)p * R * C;
  unsigned short* op = out + (long)p * R * C;
  #pragma unroll
  for (int i = 0; i < 32; i += 8)
    t[ty + i][tx] = ip[(long)(r0 + ty + i) * C + c0 + tx];
  __syncthreads();
  #pragma unroll
  for (int i = 0; i < 32; i += 8)
    op[(long)(c0 + ty + i) * R + r0 + tx] = f2bf(t[tx][ty + i]);
}

// fp32 -> bf16 elementwise (x shadow)
__global__ __launch_bounds__(256) void f2bf_kernel(
    const float* __restrict__ in, unsigned short* __restrict__ out)
{
  long i = ((long)blockIdx.x * 256 + threadIdx.x) * 4;
  float4 v = *(const float4*)(in + i);
  out[i + 0] = f2bf(v.x); out[i + 1] = f2bf(v.y);
  out[i + 2] = f2bf(v.z); out[i + 3] = f2bf(v.w);
}

// ---------------------------------------------------------------------------
// bf16 MFMA GEMM, global_load_lds staging, BK=64 (2 sub-steps per barrier),
// bank-conflict-free (pre-swizzled global source + swizzled read; rule 21).
// Round-10 proven configuration (no XCD swizzle: expert passthrough makes
// per-XCD sample assignment load-imbalanced).
// ---------------------------------------------------------------------------
template<int EPI, int TM, int TN>
__global__ __launch_bounds__(256) void gemm_bf16(
    const unsigned short* __restrict__ Abase, long aBatch, int K, int lda,
    const unsigned short* __restrict__ WTbase, long wStride,
    const float* __restrict__ xpass,
    const int* __restrict__ expert_id, int layer,
    float* __restrict__ Cf, unsigned short* __restrict__ Cbh,
    unsigned short* __restrict__ Cbh2,
    int ldc, long cBatch)
{
  constexpr int IF = TM / 32;
  constexpr int JF = TN / 32;
  constexpr int AST = TM / 4;
  constexpr int BST = TN / 4;

  const int b = blockIdx.z;
  const int eid = expert_id[b];
  const int m0 = blockIdx.y * TM, n0 = blockIdx.x * TN;
  const int tid = threadIdx.x;

  if (eid == 0) {
    if (EPI == 2) {
      float* Co = Cf + (long)b * cBatch;
      const float* xp = xpass + (long)b * L_SZ * DM;
      for (int i = tid; i < TM * TN; i += 256) {
        int r = m0 + (i / TN), c = n0 + (i % TN);
        Co[(long)r * ldc + c] = xp[(long)r * DM + c];
      }
    }
    return;
  }
  const int e = min(max(eid - 1, 0), NE - 1);
  const unsigned short* A = Abase + (long)b * aBatch;
  const unsigned short* WT = WTbase + (long)(e * NL + layer) * wStride;

  __shared__ unsigned short As[TM * 64];   // [2 k-blocks][TM][32]
  __shared__ unsigned short Bs[TN * 64];

  const int w = tid >> 6, lane = tid & 63;
  const int srow = lane >> 2;
  const int sgsw = ((lane & 3) ^ ((srow >> 1) & 3)) * 8;  // swizzled k-chunk

  const unsigned short* aG0 = A + (long)(m0 + w * AST + srow) * lda + sgsw;
  const unsigned short* aG1 = aG0 + 16 * lda;
  unsigned short* aL0 = As + (w * AST) * 32;
  unsigned short* aL1 = As + (w * AST + 16) * 32;
  const unsigned short* bG0 = WT + (long)(n0 + w * BST + srow) * K + sgsw;
  const unsigned short* bG1 = bG0 + 16 * K;
  unsigned short* bL0 = Bs + (w * BST) * 32;
  unsigned short* bL1 = Bs + (w * BST + 16) * 32;

  const int wm = w >> 1, wn = w & 1;
  const int lo = lane & 15, hi = lane >> 4;
  int aoff[IF], boff[JF];
  #pragma unroll
  for (int i = 0; i < IF; ++i)
    aoff[i] = (wm * (TM / 2) + i * 16 + lo) * 32 + (hi ^ ((lo >> 1) & 3)) * 8;
  #pragma unroll
  for (int j = 0; j < JF; ++j)
    boff[j] = (wn * (TN / 2) + j * 16 + lo) * 32 + (hi ^ ((lo >> 1) & 3)) * 8;

  f32x4 acc[IF][JF] = {};

  for (int k0 = 0; k0 < K; k0 += 64) {
    glds16(aG0 + k0, aL0);
    if (AST == 32) glds16(aG1 + k0, aL1);
    glds16(aG0 + k0 + 32, aL0 + TM * 32);
    if (AST == 32) glds16(aG1 + k0 + 32, aL1 + TM * 32);
    glds16(bG0 + k0, bL0);
    if (BST == 32) glds16(bG1 + k0, bL1);
    glds16(bG0 + k0 + 32, bL0 + TN * 32);
    if (BST == 32) glds16(bG1 + k0 + 32, bL1 + TN * 32);
    __syncthreads();

    #pragma unroll
    for (int kk = 0; kk < 2; ++kk) {
      bf16x8 af[IF], bfr[JF];
      #pragma unroll
      for (int i = 0; i < IF; ++i)
        af[i] = *(const bf16x8*)(As + kk * TM * 32 + aoff[i]);
      #pragma unroll
      for (int j = 0; j < JF; ++j)
        bfr[j] = *(const bf16x8*)(Bs + kk * TN * 32 + boff[j]);
      #pragma unroll
      for (int i = 0; i < IF; ++i)
        #pragma unroll
        for (int j = 0; j < JF; ++j)
          acc[i][j] = __builtin_amdgcn_mfma_f32_16x16x32_bf16(af[i], bfr[j], acc[i][j], 0, 0, 0);
    }
    __syncthreads();
  }

  #pragma unroll
  for (int i = 0; i < IF; ++i) {
    #pragma unroll
    for (int j = 0; j < JF; ++j) {
      #pragma unroll
      for (int r = 0; r < 4; ++r) {
        int row = m0 + wm * (TM / 2) + i * 16 + hi * 4 + r;
        int col = n0 + wn * (TN / 2) + j * 16 + lo;
        float v = acc[i][j][r];
        if (EPI == 0 || EPI == 2) {
          (Cf + (long)b * cBatch)[(long)row * ldc + col] = v;
        } else if (EPI == 4) {
          (Cbh + (long)b * cBatch)[(long)row * ldc + col] = f2bf(v);
        } else {  // EPI 3: split xc | res, both bf16
          if (col < DI)
            (Cbh + (long)b * cBatch)[(long)row * DI + col] = f2bf(v);
          else
            (Cbh2 + (long)b * cBatch)[(long)row * DI + (col - DI)] = f2bf(v);
        }
      }
    }
  }
}

// ---------------------------------------------------------------------------
// dt GEMM (fp32 A, K=32): DT = softplus(PR[:, :32] @ W_dt + b_dt), bf16 out.
// ---------------------------------------------------------------------------
__global__ __launch_bounds__(256) void gemm_dt(
    const float* __restrict__ PRb, const unsigned short* __restrict__ WTbase,
    const float* __restrict__ biasBase,
    const int* __restrict__ expert_id, int layer,
    unsigned short* __restrict__ DTout)
{
  const int b = blockIdx.z;
  const int eid = expert_id[b];
  if (eid == 0) return;
  const int e = min(max(eid - 1, 0), NE - 1);
  const int m0 = blockIdx.y * 128, n0 = blockIdx.x * 128;
  const int tid = threadIdx.x;
  const float* A = PRb + (long)b * L_SZ * 64;
  const unsigned short* WT = WTbase + (long)(e * NL + layer) * DI * DTR;

  __shared__ unsigned short As[128 * 32];
  __shared__ unsigned short Bs[128 * 32];

  const int sr = tid >> 2, sg = tid & 3;
  const int slot = sg ^ ((sr >> 1) & 3);

  {
    float4 fa0 = *(const float4*)(A + (long)(m0 + sr) * 64 + sg * 8);
    float4 fa1 = *(const float4*)(A + (long)(m0 + sr) * 64 + sg * 8 + 4);
    float4 fb0 = *(const float4*)(A + (long)(m0 + sr + 64) * 64 + sg * 8);
    float4 fb1 = *(const float4*)(A + (long)(m0 + sr + 64) * 64 + sg * 8 + 4);
    u16x8 w0 = *(const u16x8*)(WT + (long)(n0 + sr) * DTR + sg * 8);
    u16x8 w1 = *(const u16x8*)(WT + (long)(n0 + sr + 64) * DTR + sg * 8);
    u16x8 ha = {f2bf(fa0.x), f2bf(fa0.y), f2bf(fa0.z), f2bf(fa0.w),
                f2bf(fa1.x), f2bf(fa1.y), f2bf(fa1.z), f2bf(fa1.w)};
    u16x8 hb = {f2bf(fb0.x), f2bf(fb0.y), f2bf(fb0.z), f2bf(fb0.w),
                f2bf(fb1.x), f2bf(fb1.y), f2bf(fb1.z), f2bf(fb1.w)};
    *(u16x8*)(As + sr * 32 + slot * 8) = ha;
    *(u16x8*)(As + (sr + 64) * 32 + slot * 8) = hb;
    *(u16x8*)(Bs + sr * 32 + slot * 8) = w0;
    *(u16x8*)(Bs + (sr + 64) * 32 + slot * 8) = w1;
  }
  __syncthreads();

  const int lane = tid & 63, w = tid >> 6;
  const int wm = w >> 1, wn = w & 1;
  const int lo = lane & 15, hi = lane >> 4;
  f32x4 acc[4][4] = {};
  bf16x8 af[4], bfr[4];
  #pragma unroll
  for (int i = 0; i < 4; ++i) {
    int r = wm * 64 + i * 16 + lo;
    af[i] = *(const bf16x8*)(As + r * 32 + (hi ^ ((r >> 1) & 3)) * 8);
  }
  #pragma unroll
  for (int j = 0; j < 4; ++j) {
    int r = wn * 64 + j * 16 + lo;
    bfr[j] = *(const bf16x8*)(Bs + r * 32 + (hi ^ ((r >> 1) & 3)) * 8);
  }
  #pragma unroll
  for (int i = 0; i < 4; ++i)
    #pragma unroll
    for (int j = 0; j < 4; ++j)
      acc[i][j] = __builtin_amdgcn_mfma_f32_16x16x32_bf16(af[i], bfr[j], acc[i][j], 0, 0, 0);

  const float* bias = biasBase + (long)(e * NL + layer) * DI;
  unsigned short* Cb = DTout + (long)b * L_SZ * DI;
  #pragma unroll
  for (int i = 0; i < 4; ++i)
    #pragma unroll
    for (int j = 0; j < 4; ++j)
      #pragma unroll
      for (int r = 0; r < 4; ++r) {
        int row = m0 + wm * 64 + i * 16 + hi * 4 + r;
        int col = n0 + wn * 64 + j * 16 + lo;
        float v = softplus_fast(acc[i][j][r] + bias[col]);
        Cb[(long)row * DI + col] = f2bf(v);
      }
}

// ---------------------------------------------------------------------------
// Causal depthwise conv (DC=4) + SiLU, t-blocked.
// ---------------------------------------------------------------------------
__global__ __launch_bounds__(256) void conv_silu_kernel(
    const unsigned short* __restrict__ XCP,
    const float* __restrict__ conv_w, const float* __restrict__ conv_b,
    const int* __restrict__ expert_id, int layer,
    unsigned short* __restrict__ XCbf)
{
  const int idx = blockIdx.x * 256 + threadIdx.x;
  const int d8 = idx & 127;
  const int tb = (idx >> 7) & (L_SZ / TPER - 1);
  const int b = idx >> 15;
  const int eid = expert_id[b];
  if (eid == 0) return;
  const int e = min(max(eid - 1, 0), NE - 1);
  const int d0 = d8 * 8;
  const int t0 = tb * TPER;

  const float* cwp = conv_w + ((long)(e * NL + layer) * DI + d0) * DC;
  float4 w4[8];
  #pragma unroll
  for (int j = 0; j < 8; ++j) w4[j] = *(const float4*)(cwp + j * 4);
  float cb[8];
  {
    const float* cbp = conv_b + (long)(e * NL + layer) * DI + d0;
    float4 c0 = *(const float4*)(cbp);
    float4 c1 = *(const float4*)(cbp + 4);
    cb[0] = c0.x; cb[1] = c0.y; cb[2] = c0.z; cb[3] = c0.w;
    cb[4] = c1.x; cb[5] = c1.y; cb[6] = c1.z; cb[7] = c1.w;
  }

  const unsigned short* base = XCP + ((long)b * L_SZ + t0) * DI + d0;
  u16x8 r[TPER + 3];
  #pragma unroll
  for (int i = 0; i < TPER + 3; ++i) {
    if (t0 - 3 + i < 0) {
      u16x8 z = {0, 0, 0, 0, 0, 0, 0, 0};
      r[i] = z;
    } else {
      r[i] = *(const u16x8*)(base + (long)(i - 3) * DI);
    }
  }

  unsigned short* ob = XCbf + ((long)b * L_SZ + t0) * DI + d0;
  #pragma unroll
  for (int j = 0; j < TPER; ++j) {
    u16x8 o;
    #pragma unroll
    for (int ch = 0; ch < 8; ++ch) {
      float acc = cb[ch];
      acc = fmaf(bf2f(r[j + 0][ch]), w4[ch].x, acc);
      acc = fmaf(bf2f(r[j + 1][ch]), w4[ch].y, acc);
      acc = fmaf(bf2f(r[j + 2][ch]), w4[ch].z, acc);
      acc = fmaf(bf2f(r[j + 3][ch]), w4[ch].w, acc);
      float v = acc / (1.f + __expf(-acc));
      o[ch] = f2bf(v);
    }
    *(u16x8*)(ob + (long)j * DI) = o;
  }
}

// ---------------------------------------------------------------------------
// Chunked scan pass 1: local scan from h=0 -> Hws (h_end, bf16), Sws (sum dt).
// 4-t software pipeline: scalar loads hoisted per 4-t batch.
// ---------------------------------------------------------------------------
__global__ __launch_bounds__(256) void scan_p1(
    const unsigned short* __restrict__ DTb, const unsigned short* __restrict__ XCbf,
    const float* __restrict__ PR, const float* __restrict__ A_log,
    const int* __restrict__ expert_id, int layer,
    unsigned short* __restrict__ Hws, float* __restrict__ Sws)
{
  const int b = blockIdx.z, c = blockIdx.y;
  const int eid = expert_id[b];
  if (eid == 0) return;
  const int e = min(max(eid - 1, 0), NE - 1);
  const int d = blockIdx.x * 256 + threadIdx.x;
  const int t0 = c * TC2;

  __shared__ float sB[TC2][16];
  const float* prb = PR + (long)b * L_SZ * 64;
  for (int i = threadIdx.x; i < TC2 * 16; i += 256) {
    int t = i >> 4, s = i & 15;
    sB[t][s] = prb[(long)(t0 + t) * 64 + DTR + s];
  }

  float Aval[16];
  const float* al = A_log + ((long)(e * NL + layer) * DI + d) * DS;
  #pragma unroll
  for (int s = 0; s < 16; ++s) Aval[s] = -__expf(al[s]);
  bool geo = true;
  #pragma unroll
  for (int s = 1; s < 16; ++s)
    geo = geo && (fabsf(Aval[s] - Aval[0] * (s + 1)) <= 1e-4f * (s + 1));

  float h[16];
  #pragma unroll
  for (int s = 0; s < 16; ++s) h[s] = 0.f;
  float S = 0.f;

  const unsigned short* dtp = DTb + ((long)b * L_SZ + t0) * DI + d;
  const unsigned short* xcp = XCbf + ((long)b * L_SZ + t0) * DI + d;
  __syncthreads();

  const float A0 = Aval[0];
  for (int t4 = 0; t4 < TC2; t4 += 4) {
    float dt4[4], xc4[4];
    #pragma unroll
    for (int k = 0; k < 4; ++k) {
      dt4[k] = bf2f(dtp[(long)(t4 + k) * DI]);
      xc4[k] = bf2f(xcp[(long)(t4 + k) * DI]);
    }
    if (geo) {
      #pragma unroll
      for (int k = 0; k < 4; ++k) {
        int t = t4 + k;
        float dt = dt4[k];
        S += dt;
        float dx = dt * xc4[k];
        float4 b0 = *(const float4*)&sB[t][0];
        float4 b1 = *(const float4*)&sB[t][4];
        float4 b2 = *(const float4*)&sB[t][8];
        float4 b3 = *(const float4*)&sB[t][12];
        float bv[16] = {b0.x, b0.y, b0.z, b0.w, b1.x, b1.y, b1.z, b1.w,
                        b2.x, b2.y, b2.z, b2.w, b3.x, b3.y, b3.z, b3.w};
        float ee[16];
        pow16(__expf(dt * A0), ee);
        #pragma unroll
        for (int s = 0; s < 16; ++s)
          h[s] = fmaf(ee[s], h[s], dx * bv[s]);
      }
    } else {
      #pragma unroll
      for (int k = 0; k < 4; ++k) {
        int t = t4 + k;
        float dt = dt4[k];
        S += dt;
        float dx = dt * xc4[k];
        float4 b0 = *(const float4*)&sB[t][0];
        float4 b1 = *(const float4*)&sB[t][4];
        float4 b2 = *(const float4*)&sB[t][8];
        float4 b3 = *(const float4*)&sB[t][12];
        float bv[16] = {b0.x, b0.y, b0.z, b0.w, b1.x, b1.y, b1.z, b1.w,
                        b2.x, b2.y, b2.z, b2.w, b3.x, b3.y, b3.z, b3.w};
        #pragma unroll
        for (int s = 0; s < 16; ++s)
          h[s] = fmaf(__expf(dt * Aval[s]), h[s], dx * bv[s]);
      }
    }
  }

  const long hoff = (((long)b * NCH + c) * DI + d) * 16;
  u16x8 h0, h1;
  #pragma unroll
  for (int s = 0; s < 8; ++s) { h0[s] = f2bf(h[s]); h1[s] = f2bf(h[s + 8]); }
  *(u16x8*)&Hws[hoff] = h0;
  *(u16x8*)&Hws[hoff + 8] = h1;
  Sws[((long)b * NCH + c) * DI + d] = S;
}

// ---------------------------------------------------------------------------
// Chunk combine (in-place, bf16 Hws; fp32 recursion in-register)
// ---------------------------------------------------------------------------
__global__ __launch_bounds__(256) void scan_combine(
    unsigned short* __restrict__ Hws, const float* __restrict__ Sws,
    const float* __restrict__ A_log,
    const int* __restrict__ expert_id, int layer)
{
  const int gid = blockIdx.x * 256 + threadIdx.x;
  const int s = gid & 15;
  const int d = (gid >> 4) & (DI - 1);
  const int b = gid >> 14;
  const int eid = expert_id[b];
  if (eid == 0) return;
  const int e = min(max(eid - 1, 0), NE - 1);
  const float Aval = -__expf(A_log[((long)(e * NL + layer) * DI + d) * DS + s]);
  float h = 0.f;
  for (int c = 0; c < NCH; ++c) {
    const long off = (((long)b * NCH + c) * DI + d) * 16 + s;
    float q = bf2f(Hws[off]);
    float Sc = Sws[((long)b * NCH + c) * DI + d];
    Hws[off] = f2bf(h);
    h = fmaf(__expf(Aval * Sc), h, q);
  }
}

// ---------------------------------------------------------------------------
// Chunked scan pass 2: re-scan seeded with h_in (bf16); y -> bf16.
// 4-t software pipeline + 4-way split y accumulator + binary-power ee.
// ---------------------------------------------------------------------------
__global__ __launch_bounds__(256) void scan_p2(
    const unsigned short* __restrict__ DTb, const unsigned short* __restrict__ XCbf,
    const unsigned short* __restrict__ RESb, const float* __restrict__ PR,
    const float* __restrict__ A_log, const float* __restrict__ Dw,
    const unsigned short* __restrict__ Hws,
    const int* __restrict__ expert_id, int layer,
    unsigned short* __restrict__ Ybf)
{
  const int b = blockIdx.z, c = blockIdx.y;
  const int eid = expert_id[b];
  if (eid == 0) return;
  const int e = min(max(eid - 1, 0), NE - 1);
  const int d = blockIdx.x * 256 + threadIdx.x;
  const int t0 = c * TC2;

  __shared__ float sBC[TC2][32];
  const float* prb = PR + (long)b * L_SZ * 64;
  for (int i = threadIdx.x; i < TC2 * 32; i += 256) {
    int t = i >> 5, j = i & 31;
    sBC[t][j] = prb[(long)(t0 + t) * 64 + DTR + j];
  }

  float Aval[16];
  const float* al = A_log + ((long)(e * NL + layer) * DI + d) * DS;
  #pragma unroll
  for (int s = 0; s < 16; ++s) Aval[s] = -__expf(al[s]);
  bool geo = true;
  #pragma unroll
  for (int s = 1; s < 16; ++s)
    geo = geo && (fabsf(Aval[s] - Aval[0] * (s + 1)) <= 1e-4f * (s + 1));

  float h[16];
  const long hoff = (((long)b * NCH + c) * DI + d) * 16;
  {
    u16x8 h0 = *(const u16x8*)&Hws[hoff];
    u16x8 h1 = *(const u16x8*)&Hws[hoff + 8];
    #pragma unroll
    for (int s = 0; s < 8; ++s) { h[s] = bf2f(h0[s]); h[s + 8] = bf2f(h1[s]); }
  }
  const float Dd = Dw[(long)(e * NL + layer) * DI + d];

  const unsigned short* dtp = DTb + ((long)b * L_SZ + t0) * DI + d;
  const unsigned short* xcp = XCbf + ((long)b * L_SZ + t0) * DI + d;
  const unsigned short* rsp = RESb + ((long)b * L_SZ + t0) * DI + d;
  unsigned short* yb = Ybf + ((long)b * L_SZ + t0) * DI + d;
  __syncthreads();

  const float A0 = Aval[0];
  for (int t4 = 0; t4 < TC2; t4 += 4) {
    float dt4[4], xc4[4], rs4[4];
    #pragma unroll
    for (int k = 0; k < 4; ++k) {
      dt4[k] = bf2f(dtp[(long)(t4 + k) * DI]);
      xc4[k] = bf2f(xcp[(long)(t4 + k) * DI]);
      rs4[k] = bf2f(rsp[(long)(t4 + k) * DI]);
    }
    unsigned short yo[4];
    #pragma unroll
    for (int k = 0; k < 4; ++k) {
      int t = t4 + k;
      float dt = dt4[k], xc = xc4[k], res = rs4[k];
      float dx = dt * xc;
      float4 b0 = *(const float4*)&sBC[t][0];
      float4 b1 = *(const float4*)&sBC[t][4];
      float4 b2 = *(const float4*)&sBC[t][8];
      float4 b3 = *(const float4*)&sBC[t][12];
      float4 c0 = *(const float4*)&sBC[t][16];
      float4 c1 = *(const float4*)&sBC[t][20];
      float4 c2 = *(const float4*)&sBC[t][24];
      float4 c3 = *(const float4*)&sBC[t][28];
      float bv[16] = {b0.x, b0.y, b0.z, b0.w, b1.x, b1.y, b1.z, b1.w,
                      b2.x, b2.y, b2.z, b2.w, b3.x, b3.y, b3.z, b3.w};
      float cv[16] = {c0.x, c0.y, c0.z, c0.w, c1.x, c1.y, c1.z, c1.w,
                      c2.x, c2.y, c2.z, c2.w, c3.x, c3.y, c3.z, c3.w};
      float y0 = 0.f, y1 = 0.f, y2 = 0.f, y3 = 0.f;
      if (geo) {
        float ee[16];
        pow16(__expf(dt * A0), ee);
        #pragma unroll
        for (int s = 0; s < 16; s += 4) {
          h[s]     = fmaf(ee[s],     h[s],     dx * bv[s]);
          h[s + 1] = fmaf(ee[s + 1], h[s + 1], dx * bv[s + 1]);
          h[s + 2] = fmaf(ee[s + 2], h[s + 2], dx * bv[s + 2]);
          h[s + 3] = fmaf(ee[s + 3], h[s + 3], dx * bv[s + 3]);
          y0 = fmaf(h[s],     cv[s],     y0);
          y1 = fmaf(h[s + 1], cv[s + 1], y1);
          y2 = fmaf(h[s + 2], cv[s + 2], y2);
          y3 = fmaf(h[s + 3], cv[s + 3], y3);
        }
      } else {
        #pragma unroll
        for (int s = 0; s < 16; s += 4) {
          h[s]     = fmaf(__expf(dt * Aval[s]),     h[s],     dx * bv[s]);
          h[s + 1] = fmaf(__expf(dt * Aval[s + 1]), h[s + 1], dx * bv[s + 1]);
          h[s + 2] = fmaf(__expf(dt * Aval[s + 2]), h[s + 2], dx * bv[s + 2]);
          h[s + 3] = fmaf(__expf(dt * Aval[s + 3]), h[s + 3], dx * bv[s + 3]);
          y0 = fmaf(h[s],     cv[s],     y0);
          y1 = fmaf(h[s + 1], cv[s + 1], y1);
          y2 = fmaf(h[s + 2], cv[s + 2], y2);
          y3 = fmaf(h[s + 3], cv[s + 3], y3);
        }
      }
      float y = (y0 + y1) + (y2 + y3);
      y = fmaf(Dd, xc, y);
      float sil = res / (1.f + __expf(-res));
      yo[k] = f2bf(y * sil);
    }
    #pragma unroll
    for (int k = 0; k < 4; ++k)
      yb[(long)(t4 + k) * DI] = yo[k];
  }
}

// ---------------------------------------------------------------------------
extern "C" void kernel_launch(void* const* d_in, const int* in_sizes, int n_in,
                              void* d_out, int out_size, void* d_ws, size_t ws_size,
                              hipStream_t stream)
{
  const float* x      = (const float*)d_in[0];
  const int*   eidp   = (const int*)d_in[1];
  const float* W_in   = (const float*)d_in[2];
  const float* conv_w = (const float*)d_in[3];
  const float* conv_b = (const float*)d_in[4];
  const float* W_x    = (const float*)d_in[5];
  const float* W_dt   = (const float*)d_in[6];
  const float* b_dt   = (const float*)d_in[7];
  const float* A_log  = (const float*)d_in[8];
  const float* Dw     = (const float*)d_in[9];
  const float* W_out  = (const float*)d_in[10];
  float* out = (float*)d_out;
  float* ws  = (float*)d_ws;

  // workspace layout — total ~191 MB (< proven-safe 265.8 MB)
  float* PR  = ws;                          //  1,048,576 f32 ( 4 MB)
  float* Sws = PR + 1048576L;               //    524,288 f32 ( 2 MB)
  unsigned short* Hws  = (unsigned short*)(Sws + 524288L);  // 8,388,608 bf16 (16 MB)
  unsigned short* DTb  = Hws + 8388608L;                    // 32 MB
  unsigned short* XCP  = DTb + 16777216L;                   // 32 MB
  unsigned short* Ybf  = XCP;                               // overlay (disjoint liveness)
  unsigned short* XCbf = XCP + 16777216L;                   // 32 MB
  unsigned short* RESb = XCbf + 16777216L;                  // 32 MB
  unsigned short* XB   = RESb + 16777216L;                  // 16 MB (x shadow / XN)
  unsigned short* WinT  = XB + 8388608L;                    // 16 MB
  unsigned short* WoutT = WinT + 8388608L;                  //  8 MB
  unsigned short* WxT   = WoutT + 4194304L;                 //  1 MB
  unsigned short* WdtT  = WxT + 524288L;                    // 0.5 MB

  transpose_w_kernel<<<dim3(2 * DI / 32, DM / 32, NE * NL), 256, 0, stream>>>(
      W_in, WinT, DM, 2 * DI);
  transpose_w_kernel<<<dim3(DM / 32, DI / 32, NE * NL), 256, 0, stream>>>(
      W_out, WoutT, DI, DM);
  transpose_w_kernel<<<dim3(2, DI / 32, NE * NL), 256, 0, stream>>>(
      W_x, WxT, DI, 64);
  transpose_w_kernel<<<dim3(DI / 32, 1, NE * NL), 256, 0, stream>>>(
      W_dt, WdtT, DTR, DI);
  f2bf_kernel<<<8192, 256, 0, stream>>>(x, XB);

  for (int l = 0; l < NL; ++l) {
    // 1) xr = xin @ W_in  (M=2048 N=2048 K=512): split -> XCP bf16 | RESb bf16
    gemm_bf16<3, 128, 128><<<dim3(2 * DI / 128, L_SZ / 128, B_SZ), 256, 0, stream>>>(
        XB, (long)L_SZ * DM, DM, DM, WinT, (long)(2 * DI) * DM,
        nullptr, eidp, l, nullptr, XCP, RESb, 0, (long)L_SZ * DI);

    // 2) conv + silu -> XCbf bf16
    conv_silu_kernel<<<B_SZ * (L_SZ / TPER) * 128 / 256, 256, 0, stream>>>(
        XCP, conv_w, conv_b, eidp, l, XCbf);

    // 3) proj = xc @ W_x -> PR fp32  (M=2048 N=64 K=1024, TM=TN=64)
    gemm_bf16<0, 64, 64><<<dim3(1, L_SZ / 64, B_SZ), 256, 0, stream>>>(
        XCbf, (long)L_SZ * DI, DI, DI, WxT, (long)64 * DI,
        nullptr, eidp, l, PR, nullptr, nullptr, 64, (long)L_SZ * 64);

    // 4) dt = softplus(PR[:,:32] @ W_dt + b_dt) -> DTb bf16
    gemm_dt<<<dim3(DI / 128, L_SZ / 128, B_SZ), 256, 0, stream>>>(
        PR, WdtT, b_dt, eidp, l, DTb);

    // 5) chunked scan -> Ybf bf16 (overlays XCP, dead after conv)
    scan_p1<<<dim3(DI / 256, NCH, B_SZ), 256, 0, stream>>>(
        DTb, XCbf, PR, A_log, eidp, l, Hws, Sws);
    scan_combine<<<(B_SZ * DI * DS) / 256, 256, 0, stream>>>(
        Hws, Sws, A_log, eidp, l);
    scan_p2<<<dim3(DI / 256, NCH, B_SZ), 256, 0, stream>>>(
        DTb, XCbf, RESb, PR, A_log, Dw, Hws, eidp, l, Ybf);

    // 6) y @ W_out  (M=2048 N=512 K=1024)
    if (l == NL - 1) {
      gemm_bf16<2, 128, 128><<<dim3(DM / 128, L_SZ / 128, B_SZ), 256, 0, stream>>>(
          Ybf, (long)L_SZ * DI, DI, DI, WoutT, (long)DM * DI,
          x, eidp, l, out, nullptr, nullptr, DM, (long)L_SZ * DM);
    } else {
      gemm_bf16<4, 128, 128><<<dim3(DM / 128, L_SZ / 128, B_SZ), 256, 0, stream>>>(
          Ybf, (long)L_SZ * DI, DI, DI, WoutT, (long)DM * DI,
          nullptr, eidp, l, nullptr, XB, nullptr, DM, (long)L_SZ * DM);
    }
  }
}